// Round 1
// baseline (2679.262 us; speedup 1.0000x reference)
//
#include <hip/hip_runtime.h>

#define PP 16
#define NN 128
#define CC 256
#define SS 64
#define HH 64
#define LW 72   // LDS row stride in floats: 72*4=288 B, 16B-aligned rows

// Transpose w31_b [P][C][HID][1] -> [P][HID][C]
__global__ void k_t31(const float* __restrict__ in, float* __restrict__ out) {
    int i = blockIdx.x * 256 + threadIdx.x;   // [0, 16*64*256)
    int p = i >> 14;
    int h = (i >> 8) & 63;
    int c = i & 255;
    out[i] = in[(((p << 8) | c) << 6) | h];
}

// Transpose w33_b [P][C][HID][3] -> [P][3][HID][C]
__global__ void k_t33(const float* __restrict__ in, float* __restrict__ out) {
    int i = blockIdx.x * 256 + threadIdx.x;   // [0, 16*3*64*256)
    int q = i >> 14;                          // p*3 + tap
    int p = q / 3, tap = q - p * 3;
    int h = (i >> 8) & 63;
    int c = i & 255;
    out[i] = in[((((p << 8) | c) << 6) | h) * 3 + tap];
}

template <bool TR>
__global__ __launch_bounds__(512, 2)
void fused_kernel(const float* __restrict__ x,
                  const float* __restrict__ w31a, const float* __restrict__ w31b,
                  const float* __restrict__ w33a, const float* __restrict__ w33b,
                  const float* __restrict__ t31, const float* __restrict__ t33,
                  float* __restrict__ out) {
    __shared__ float lds[(CC + HH + HH) * LW];   // 110,592 B
    float* xs  = lds;                  // [256][72], data at col 4+s, halo zeros
    float* h31 = lds + CC * LW;        // [64][72]
    float* h33 = h31 + HH * LW;        // [64][72]

    const int t = threadIdx.x;
    const int n = blockIdx.x, p = blockIdx.y;
    const int lane = t & 63;

    // ---------- phase 0: stage x tile, zero halos ----------
    {
        const float4* src = (const float4*)(x + (size_t)(p * NN + n) * (CC * SS));
        #pragma unroll
        for (int i = 0; i < 8; ++i) {
            int f4 = t + i * 512;          // [0,4096) float4s
            int c = f4 >> 4, q = f4 & 15;
            *(float4*)(xs + c * LW + 4 + q * 4) = src[f4];
        }
        if (t < 256) {
            *(float4*)(xs + t * LW)      = make_float4(0.f, 0.f, 0.f, 0.f);
            *(float4*)(xs + t * LW + 68) = make_float4(0.f, 0.f, 0.f, 0.f);
        } else if (t < 320) {
            int h = t - 256;
            *(float4*)(h33 + h * LW)      = make_float4(0.f, 0.f, 0.f, 0.f);
            *(float4*)(h33 + h * LW + 68) = make_float4(0.f, 0.f, 0.f, 0.f);
        }
    }
    __syncthreads();

    // ---------- phase 1: conv1 + leaky-relu -> h31/h33 in LDS ----------
    {
        const int grp  = t >> 6;           // 0..7 (wave id)
        const int conv = grp & 1;          // 0: 3x1 branch (w31a), 1: 3x3 (w33a)
        const int hid0 = (grp >> 1) * 16;
        const float4* wa4 = (const float4*)((conv ? w33a : w31a) + (size_t)p * (HH * CC * 3));
        float acc[16];
        #pragma unroll
        for (int h = 0; h < 16; ++h) acc[h] = 0.f;

        for (int c4 = 0; c4 < 64; ++c4) {
            float xm[4], x0[4], xp[4];
            #pragma unroll
            for (int j = 0; j < 4; ++j) {
                const float* r = xs + (c4 * 4 + j) * LW + 4 + lane;
                xm[j] = r[-1]; x0[j] = r[0]; xp[j] = r[1];
            }
            #pragma unroll
            for (int h = 0; h < 16; ++h) {
                const float4* wp = wa4 + (hid0 + h) * 192 + c4 * 3;
                float4 w0 = wp[0], w1 = wp[1], w2 = wp[2];
                float a = acc[h];
                a += xm[0]*w0.x + x0[0]*w0.y + xp[0]*w0.z;
                a += xm[1]*w0.w + x0[1]*w1.x + xp[1]*w1.y;
                a += xm[2]*w1.z + x0[2]*w1.w + xp[2]*w2.x;
                a += xm[3]*w2.y + x0[3]*w2.z + xp[3]*w2.w;
                acc[h] = a;
            }
        }
        float* dst = conv ? h33 : h31;
        #pragma unroll
        for (int h = 0; h < 16; ++h) {
            float v = acc[h];
            v = v >= 0.f ? v : 0.01f * v;
            dst[(hid0 + h) * LW + 4 + lane] = v;
        }
    }
    __syncthreads();

    // ---------- phase 2: conv2 + pooling + sigmoid gate + max over s ----------
    {
        const int cg = t >> 6;
        const int c0 = cg * 32;
        float l31[32], l33[32];
        #pragma unroll
        for (int i = 0; i < 32; ++i) { l31[i] = 0.f; l33[i] = 0.f; }

        for (int hid = 0; hid < HH; ++hid) {
            const float* hr1 = h31 + hid * LW + 4 + lane;
            const float* hr3 = h33 + hid * LW + 4 + lane;
            float hv = hr1[0];
            float hm = hr3[-1], h0 = hr3[0], hp = hr3[1];
            if (TR) {
                const float4* a4 = (const float4*)(t31 + ((size_t)(p * 64 + hid) * 256 + c0));
                const float4* b0 = (const float4*)(t33 + ((size_t)((p * 3 + 0) * 64 + hid) * 256 + c0));
                const float4* b1 = (const float4*)(t33 + ((size_t)((p * 3 + 1) * 64 + hid) * 256 + c0));
                const float4* b2 = (const float4*)(t33 + ((size_t)((p * 3 + 2) * 64 + hid) * 256 + c0));
                #pragma unroll
                for (int j = 0; j < 8; ++j) {
                    float4 a = a4[j];
                    float4 u = b0[j], v = b1[j], w = b2[j];
                    l31[4*j+0] += hv * a.x; l31[4*j+1] += hv * a.y;
                    l31[4*j+2] += hv * a.z; l31[4*j+3] += hv * a.w;
                    l33[4*j+0] += hm*u.x + h0*v.x + hp*w.x;
                    l33[4*j+1] += hm*u.y + h0*v.y + hp*w.y;
                    l33[4*j+2] += hm*u.z + h0*v.z + hp*w.z;
                    l33[4*j+3] += hm*u.w + h0*v.w + hp*w.w;
                }
            } else {
                #pragma unroll
                for (int i = 0; i < 32; ++i) {
                    int c = c0 + i;
                    l31[i] += hv * w31b[((size_t)p * 256 + c) * 64 + hid];
                    const float* wb = w33b + (((size_t)p * 256 + c) * 64 + hid) * 3;
                    l33[i] += hm * wb[0] + h0 * wb[1] + hp * wb[2];
                }
            }
        }

        const size_t obase = ((size_t)p * NN + n) * CC + c0;
        #pragma unroll
        for (int i = 0; i < 32; ++i) {
            const float* r = xs + (c0 + i) * LW + 4 + lane;
            float xm2 = r[-2], xm = r[-1], x0v = r[0], xp = r[1], xp2 = r[2];
            // avg pools: count_include_pad -> zero halo + fixed divisor
            float s3 = (xm + x0v + xp) * (1.f / 3.f);
            float s5 = (xm2 + xm + x0v + xp + xp2) * 0.2f;
            // max pools: -inf padding -> bound-predicated
            float m3 = x0v;
            if (lane >= 1)  m3 = fmaxf(m3, xm);
            if (lane <= 62) m3 = fmaxf(m3, xp);
            float m5 = m3;
            if (lane >= 2)  m5 = fmaxf(m5, xm2);
            if (lane <= 61) m5 = fmaxf(m5, xp2);
            float f31 = s3 + m3, f33 = s5 + m5;
            float g = f31 / (1.f + __expf(-l31[i])) + f33 / (1.f + __expf(-l33[i]));
            #pragma unroll
            for (int off = 32; off; off >>= 1)
                g = fmaxf(g, __shfl_xor(g, off));
            if (lane == 0) out[obase + i] = g;
        }
    }
}

extern "C" void kernel_launch(void* const* d_in, const int* in_sizes, int n_in,
                              void* d_out, int out_size, void* d_ws, size_t ws_size,
                              hipStream_t stream) {
    const float* x    = (const float*)d_in[0];
    const float* w31a = (const float*)d_in[1];
    const float* w31b = (const float*)d_in[2];
    const float* w33a = (const float*)d_in[3];
    const float* w33b = (const float*)d_in[4];
    float* out = (float*)d_out;

    float* t31 = (float*)d_ws;            // 262144 floats (1 MiB)
    float* t33 = t31 + 262144;            // 786432 floats (3 MiB)
    const bool tr = ws_size >= (size_t)(262144 + 786432) * sizeof(float);

    dim3 grid(NN, PP);
    if (tr) {
        k_t31<<<1024, 256, 0, stream>>>(w31b, t31);
        k_t33<<<3072, 256, 0, stream>>>(w33b, t33);
        fused_kernel<true><<<grid, 512, 0, stream>>>(x, w31a, w31b, w33a, w33b, t31, t33, out);
    } else {
        fused_kernel<false><<<grid, 512, 0, stream>>>(x, w31a, w31b, w33a, w33b, nullptr, nullptr, out);
    }
}

// Round 2
// 303.625 us; speedup vs baseline: 8.8242x; 8.8242x over previous
//
#include <hip/hip_runtime.h>

#define PP 16
#define NN 128
#define CC 256
#define SS 64
#define HH 64

typedef __attribute__((ext_vector_type(8))) short v8bf;
typedef __attribute__((ext_vector_type(4))) float f32x4;
typedef __attribute__((ext_vector_type(4))) unsigned short u16x4;

__device__ __forceinline__ unsigned short f2bf(float f) {
    unsigned u = __float_as_uint(f);
    return (unsigned short)((u + 0x7fffu + ((u >> 16) & 1u)) >> 16);
}

// ---------------- weight repack kernels (bf16, MFMA-fragment order) ----------------
// wp1: frag index (((beta*16+p)*3+t)*8+kk)*4+mi ; lane l holds 8 bf16:
//      w[hid = mi*16 + (l&15)][c = kk*32 + 8*(l>>4) + j][tap t]
__global__ void k_pack1(const float* __restrict__ w31a, const float* __restrict__ w33a,
                        unsigned short* __restrict__ wp1) {
    int u = blockIdx.x * 256 + threadIdx.x;        // [0, 196608)
    int l = u & 63;
    int mi = (u >> 6) & 3;
    int kk = (u >> 8) & 7;
    int v = u >> 11;                               // (beta*16+p)*3 + t, [0,96)
    int t = v % 3;
    int pb = v / 3;
    int p = pb & 15, beta = pb >> 4;
    int hid = mi * 16 + (l & 15);
    int c = kk * 32 + 8 * (l >> 4);
    const float* w = (beta ? w33a : w31a) + (((size_t)(p * 64 + hid) * 256 + c) * 3 + t);
    v8bf r;
    #pragma unroll
    for (int j = 0; j < 8; ++j) r[j] = (short)f2bf(w[j * 3]);
    ((v8bf*)wp1)[u] = r;
}

// wp31: frag ((p*2+kk)*16+mt) ; lane l: w31b[cout=mt*16+(l&15)][hid=kk*32+8*(l>>4)+j]
__global__ void k_pack31(const float* __restrict__ w31b, unsigned short* __restrict__ wp31) {
    int u = blockIdx.x * 256 + threadIdx.x;        // [0, 32768)
    int l = u & 63;
    int mt = (u >> 6) & 15;
    int kk = (u >> 10) & 1;
    int p = u >> 11;
    int cout = mt * 16 + (l & 15);
    int hid = kk * 32 + 8 * (l >> 4);
    const float* w = w31b + ((size_t)(p * 256 + cout) * 64 + hid);
    v8bf r;
    #pragma unroll
    for (int j = 0; j < 8; ++j) r[j] = (short)f2bf(w[j]);
    ((v8bf*)wp31)[u] = r;
}

// wp33: frag (((p*3+t)*2+kk)*16+mt) ; lane l: w33b[cout][hid=kk*32+8*(l>>4)+j][tap t]
__global__ void k_pack33(const float* __restrict__ w33b, unsigned short* __restrict__ wp33) {
    int u = blockIdx.x * 256 + threadIdx.x;        // [0, 98304)
    int l = u & 63;
    int mt = (u >> 6) & 15;
    int kk = (u >> 10) & 1;
    int v = u >> 11;                               // p*3 + t
    int t = v % 3;
    int p = v / 3;
    int cout = mt * 16 + (l & 15);
    int hid = kk * 32 + 8 * (l >> 4);
    const float* w = w33b + (((size_t)(p * 256 + cout) * 64 + hid) * 3 + t);
    v8bf r;
    #pragma unroll
    for (int j = 0; j < 8; ++j) r[j] = (short)f2bf(w[j * 3]);
    ((v8bf*)wp33)[u] = r;
}

// ---------------- fused MFMA kernel ----------------
// LDS layout (bytes):
//   xs  fp32 [256][72]  @ 0       (73728 B)  data at col 4+s, zero halo cols 0-3, 68-71
//   xb  bf16 [66][256]  @ 73728   (33792 B)  row r = s+1 (rows 0,65 zero), XOR-swizzled
//   hb  bf16 2x[66][64] @ 107520  (16896 B)  row r = s+1, XOR-swizzled
#define XS_STRIDE 72
#define XB_OFF 73728
#define HB_OFF 107520
#define LDS_BYTES 124416

__global__ __launch_bounds__(512, 2)
void fused_mfma(const float* __restrict__ x,
                const unsigned short* __restrict__ wp1,
                const unsigned short* __restrict__ wp31,
                const unsigned short* __restrict__ wp33,
                float* __restrict__ out) {
    __shared__ __align__(16) char lds[LDS_BYTES];
    float* xs = (float*)lds;
    char* xbb = lds + XB_OFF;
    char* hbb = lds + HB_OFF;

    const int t = threadIdx.x;
    const int n = blockIdx.x, p = blockIdx.y;
    const int lane = t & 63;
    const int l15 = lane & 15, lhi = lane >> 4;
    const int w = t >> 6;

    // ---------- phase 0: stage xs (fp32) + xb (bf16 transposed, swizzled) ----------
    {
        const float4* src = (const float4*)(x + (size_t)(p * NN + n) * (CC * SS));
        #pragma unroll
        for (int i = 0; i < 8; ++i) {
            int f4 = t + i * 512;                  // [0,4096)
            int c = f4 >> 4, q = f4 & 15;
            float4 v = src[f4];
            *(float4*)(xs + c * XS_STRIDE + 4 + q * 4) = v;
            unsigned short b[4] = {f2bf(v.x), f2bf(v.y), f2bf(v.z), f2bf(v.w)};
            #pragma unroll
            for (int k = 0; k < 4; ++k) {
                int r = q * 4 + 1 + k;             // xb row = s+1
                *(unsigned short*)(xbb + r * 512 + ((c * 2) ^ ((r & 7) << 4))) = b[k];
            }
        }
        if (t < 256) {
            *(float4*)(xs + t * XS_STRIDE) = make_float4(0.f, 0.f, 0.f, 0.f);
            *(float4*)(xs + t * XS_STRIDE + 68) = make_float4(0.f, 0.f, 0.f, 0.f);
        } else if (t < 288) {
            *(float4*)(xbb + (t - 256) * 16) = make_float4(0.f, 0.f, 0.f, 0.f);          // xb row 0
        } else if (t < 320) {
            *(float4*)(xbb + 33280 + (t - 288) * 16) = make_float4(0.f, 0.f, 0.f, 0.f);  // xb row 65
        } else if (t < 352) {
            int j = t - 320;                       // hb rows 0 & 65, both branches
            int region = j >> 3;
            int base = (region >> 1) * 8448 + ((region & 1) ? 8320 : 0);
            *(float4*)(hbb + base + (j & 7) * 16) = make_float4(0.f, 0.f, 0.f, 0.f);
        }
    }
    __syncthreads();

    // ---------- phase 1: conv1 (bf16 MFMA) + leaky-relu -> hb ----------
    {
        const int beta = w & 1, mi = w >> 1;
        const v8bf* wv = (const v8bf*)wp1;
        v8bf A1[24];
        #pragma unroll
        for (int f = 0; f < 24; ++f) {             // f = tap*8 + kk
            int frag = ((beta * 16 + p) * 24 + f) * 4 + mi;
            A1[f] = wv[(size_t)frag * 64 + lane];
        }
        #pragma unroll
        for (int ni = 0; ni < 4; ++ni) {
            f32x4 acc = {0.f, 0.f, 0.f, 0.f};
            #pragma unroll
            for (int f = 0; f < 24; ++f) {
                int tp = f >> 3, kk = f & 7;
                int r = ni * 16 + l15 + tp;
                const v8bf* bp = (const v8bf*)(xbb + r * 512 +
                                               ((kk * 64 + 16 * lhi) ^ ((r & 7) << 4)));
                acc = __builtin_amdgcn_mfma_f32_16x16x32_bf16(A1[f], *bp, acc, 0, 0, 0);
            }
            int r2 = ni * 16 + l15 + 1;
            u16x4 hv;
            #pragma unroll
            for (int reg = 0; reg < 4; ++reg) {
                float v = acc[reg];
                v = v >= 0.f ? v : 0.01f * v;
                hv[reg] = f2bf(v);
            }
            *(u16x4*)(hbb + beta * 8448 + r2 * 128 +
                      ((mi * 32 + 8 * lhi) ^ ((r2 & 7) << 4))) = hv;
        }
    }
    __syncthreads();

    // ---------- phase 2: conv2 (MFMA) + pooling + gate + max over s ----------
    {
        const v8bf* w1v = (const v8bf*)wp31;
        const v8bf* w3v = (const v8bf*)wp33;
        v8bf A31[2][2], A33[3][2][2];              // [kk][mt_i], [tap][kk][mt_i]
        #pragma unroll
        for (int m = 0; m < 2; ++m) {
            int mt = w * 2 + m;
            #pragma unroll
            for (int kk = 0; kk < 2; ++kk) {
                A31[kk][m] = w1v[(size_t)((p * 2 + kk) * 16 + mt) * 64 + lane];
                #pragma unroll
                for (int tp = 0; tp < 3; ++tp)
                    A33[tp][kk][m] = w3v[(size_t)(((p * 3 + tp) * 2 + kk) * 16 + mt) * 64 + lane];
            }
        }

        const size_t obase = (size_t)(p * NN + n) * CC;
        #pragma unroll
        for (int m = 0; m < 2; ++m) {
            int mt = w * 2 + m;
            float gmax[4] = {-3.4e38f, -3.4e38f, -3.4e38f, -3.4e38f};
            #pragma unroll
            for (int ni = 0; ni < 4; ++ni) {
                f32x4 a31 = {0.f, 0.f, 0.f, 0.f}, a33 = {0.f, 0.f, 0.f, 0.f};
                #pragma unroll
                for (int kk = 0; kk < 2; ++kk) {
                    int r = ni * 16 + l15 + 1;
                    const v8bf* b1 = (const v8bf*)(hbb + r * 128 +
                                                   ((kk * 64 + 16 * lhi) ^ ((r & 7) << 4)));
                    a31 = __builtin_amdgcn_mfma_f32_16x16x32_bf16(A31[kk][m], *b1, a31, 0, 0, 0);
                }
                #pragma unroll
                for (int tp = 0; tp < 3; ++tp) {
                    #pragma unroll
                    for (int kk = 0; kk < 2; ++kk) {
                        int r = ni * 16 + l15 + tp;
                        const v8bf* b3 = (const v8bf*)(hbb + 8448 + r * 128 +
                                                       ((kk * 64 + 16 * lhi) ^ ((r & 7) << 4)));
                        a33 = __builtin_amdgcn_mfma_f32_16x16x32_bf16(A33[tp][kk][m], *b3, a33, 0, 0, 0);
                    }
                }
                int s = ni * 16 + l15;
                #pragma unroll
                for (int reg = 0; reg < 4; ++reg) {
                    int c = mt * 16 + 4 * lhi + reg;
                    const float* rx = xs + c * XS_STRIDE + 4 + s;
                    float xm2 = rx[-2], xm = rx[-1], x0 = rx[0], xp = rx[1], xp2 = rx[2];
                    float s3 = (xm + x0 + xp) * (1.f / 3.f);
                    float s5 = (xm2 + xm + x0 + xp + xp2) * 0.2f;
                    float m3 = x0;
                    if (s >= 1)  m3 = fmaxf(m3, xm);
                    if (s <= 62) m3 = fmaxf(m3, xp);
                    float m5 = m3;
                    if (s >= 2)  m5 = fmaxf(m5, xm2);
                    if (s <= 61) m5 = fmaxf(m5, xp2);
                    float g = (s3 + m3) / (1.f + __expf(-a31[reg])) +
                              (s5 + m5) / (1.f + __expf(-a33[reg]));
                    gmax[reg] = fmaxf(gmax[reg], g);
                }
            }
            #pragma unroll
            for (int reg = 0; reg < 4; ++reg) {
                float g = gmax[reg];
                #pragma unroll
                for (int msk = 8; msk; msk >>= 1) g = fmaxf(g, __shfl_xor(g, msk));
                gmax[reg] = g;
            }
            if (l15 == 0) {
                float4 o = make_float4(gmax[0], gmax[1], gmax[2], gmax[3]);
                *(float4*)(out + obase + mt * 16 + 4 * lhi) = o;
            }
        }
    }
}

// ---------------- fp32 fallback (only if ws too small) ----------------
#define LW 72
__global__ __launch_bounds__(512, 2)
void fused_fallback(const float* __restrict__ x,
                    const float* __restrict__ w31a, const float* __restrict__ w31b,
                    const float* __restrict__ w33a, const float* __restrict__ w33b,
                    float* __restrict__ out) {
    __shared__ float lds[(CC + HH + HH) * LW];
    float* xs = lds;
    float* h31 = lds + CC * LW;
    float* h33 = h31 + HH * LW;
    const int t = threadIdx.x;
    const int n = blockIdx.x, p = blockIdx.y;
    const int lane = t & 63;
    {
        const float4* src = (const float4*)(x + (size_t)(p * NN + n) * (CC * SS));
        #pragma unroll
        for (int i = 0; i < 8; ++i) {
            int f4 = t + i * 512;
            int c = f4 >> 4, q = f4 & 15;
            *(float4*)(xs + c * LW + 4 + q * 4) = src[f4];
        }
        if (t < 256) {
            *(float4*)(xs + t * LW) = make_float4(0.f, 0.f, 0.f, 0.f);
            *(float4*)(xs + t * LW + 68) = make_float4(0.f, 0.f, 0.f, 0.f);
        } else if (t < 320) {
            int h = t - 256;
            *(float4*)(h33 + h * LW) = make_float4(0.f, 0.f, 0.f, 0.f);
            *(float4*)(h33 + h * LW + 68) = make_float4(0.f, 0.f, 0.f, 0.f);
        }
    }
    __syncthreads();
    {
        const int grp = t >> 6;
        const int conv = grp & 1;
        const int hid0 = (grp >> 1) * 16;
        const float4* wa4 = (const float4*)((conv ? w33a : w31a) + (size_t)p * (HH * CC * 3));
        float acc[16];
        #pragma unroll
        for (int h = 0; h < 16; ++h) acc[h] = 0.f;
        for (int c4 = 0; c4 < 64; ++c4) {
            float xm[4], x0[4], xp[4];
            #pragma unroll
            for (int j = 0; j < 4; ++j) {
                const float* r = xs + (c4 * 4 + j) * LW + 4 + lane;
                xm[j] = r[-1]; x0[j] = r[0]; xp[j] = r[1];
            }
            #pragma unroll
            for (int h = 0; h < 16; ++h) {
                const float4* wp = wa4 + (hid0 + h) * 192 + c4 * 3;
                float4 w0 = wp[0], w1 = wp[1], w2 = wp[2];
                float a = acc[h];
                a += xm[0]*w0.x + x0[0]*w0.y + xp[0]*w0.z;
                a += xm[1]*w0.w + x0[1]*w1.x + xp[1]*w1.y;
                a += xm[2]*w1.z + x0[2]*w1.w + xp[2]*w2.x;
                a += xm[3]*w2.y + x0[3]*w2.z + xp[3]*w2.w;
                acc[h] = a;
            }
        }
        float* dst = conv ? h33 : h31;
        #pragma unroll
        for (int h = 0; h < 16; ++h) {
            float v = acc[h];
            v = v >= 0.f ? v : 0.01f * v;
            dst[(hid0 + h) * LW + 4 + lane] = v;
        }
    }
    __syncthreads();
    {
        const int cg = t >> 6;
        const int c0 = cg * 32;
        float l31[32], l33[32];
        #pragma unroll
        for (int i = 0; i < 32; ++i) { l31[i] = 0.f; l33[i] = 0.f; }
        for (int hid = 0; hid < HH; ++hid) {
            const float* hr1 = h31 + hid * LW + 4 + lane;
            const float* hr3 = h33 + hid * LW + 4 + lane;
            float hv = hr1[0];
            float hm = hr3[-1], h0 = hr3[0], hp = hr3[1];
            #pragma unroll
            for (int i = 0; i < 32; ++i) {
                int c = c0 + i;
                l31[i] += hv * w31b[((size_t)p * 256 + c) * 64 + hid];
                const float* wb = w33b + (((size_t)p * 256 + c) * 64 + hid) * 3;
                l33[i] += hm * wb[0] + h0 * wb[1] + hp * wb[2];
            }
        }
        const size_t obase = ((size_t)p * NN + n) * CC + c0;
        #pragma unroll
        for (int i = 0; i < 32; ++i) {
            const float* r = xs + (c0 + i) * LW + 4 + lane;
            float xm2 = r[-2], xm = r[-1], x0v = r[0], xp = r[1], xp2 = r[2];
            float s3 = (xm + x0v + xp) * (1.f / 3.f);
            float s5 = (xm2 + xm + x0v + xp + xp2) * 0.2f;
            float m3 = x0v;
            if (lane >= 1)  m3 = fmaxf(m3, xm);
            if (lane <= 62) m3 = fmaxf(m3, xp);
            float m5 = m3;
            if (lane >= 2)  m5 = fmaxf(m5, xm2);
            if (lane <= 61) m5 = fmaxf(m5, xp2);
            float g = (s3 + m3) / (1.f + __expf(-l31[i])) + (s5 + m5) / (1.f + __expf(-l33[i]));
            #pragma unroll
            for (int off = 32; off; off >>= 1)
                g = fmaxf(g, __shfl_xor(g, off));
            if (lane == 0) out[obase + i] = g;
        }
    }
}

extern "C" void kernel_launch(void* const* d_in, const int* in_sizes, int n_in,
                              void* d_out, int out_size, void* d_ws, size_t ws_size,
                              hipStream_t stream) {
    const float* x    = (const float*)d_in[0];
    const float* w31a = (const float*)d_in[1];
    const float* w31b = (const float*)d_in[2];
    const float* w33a = (const float*)d_in[3];
    const float* w33b = (const float*)d_in[4];
    float* out = (float*)d_out;

    // ws layout (bytes): wp1 @0 (3,145,728), wp31 @3,145,728 (524,288), wp33 @3,670,016 (1,572,864)
    const size_t need = 5242880;
    dim3 grid(NN, PP);
    if (ws_size >= need) {
        unsigned short* wp1  = (unsigned short*)d_ws;
        unsigned short* wp31 = (unsigned short*)((char*)d_ws + 3145728);
        unsigned short* wp33 = (unsigned short*)((char*)d_ws + 3670016);
        k_pack1 <<<768, 256, 0, stream>>>(w31a, w33a, wp1);
        k_pack31<<<128, 256, 0, stream>>>(w31b, wp31);
        k_pack33<<<384, 256, 0, stream>>>(w33b, wp33);
        fused_mfma<<<grid, 512, 0, stream>>>(x, wp1, wp31, wp33, out);
    } else {
        fused_fallback<<<grid, 512, 0, stream>>>(x, w31a, w31b, w33a, w33b, out);
    }
}